// Round 10
// baseline (190.854 us; speedup 1.0000x reference)
//
#include <hip/hip_runtime.h>

// Problem constants (match reference module)
#define VNX 360
#define VNY 160
#define VNZ 48
#define VC 4
static constexpr int PLANE = VNZ * VNY * VNX;   // 2,764,800 voxels per batch

typedef unsigned int u32x4 __attribute__((ext_vector_type(4)));
typedef float        f32x4 __attribute__((ext_vector_type(4)));

// ---------------------------------------------------------------------------
// Pass 1: winner[G] = 0xFFFFFFFF sentinel (in d_ws). NORMAL cached stores
// (R7 showed NT stores here regress). Grid-stride, 16B stores.
// ---------------------------------------------------------------------------
__global__ void vox_init_kernel(u32x4* __restrict__ w4, int n4) {
    int stride = gridDim.x * blockDim.x;
    u32x4 s = { ~0u, ~0u, ~0u, ~0u };
    for (int t = blockIdx.x * blockDim.x + threadIdx.x; t < n4; t += stride)
        w4[t] = s;
}

// ---------------------------------------------------------------------------
// Pass 2: per-point voxelization, first-point-wins via atomicMin(pid).
// Binning: (p - lo) * 5.0f (NOT /0.2f) — matches XLA-CPU fast-math
// reciprocal rewrite; verified bit-exact in round 4.
// ---------------------------------------------------------------------------
__global__ void vox_points_kernel(const float4* __restrict__ pts,
                                  const int* __restrict__ bidx,
                                  unsigned int* __restrict__ winner,
                                  int n) {
    int i = blockIdx.x * blockDim.x + threadIdx.x;
    if (i >= n) return;

    float4 p = pts[i];  // x, y, z, power
    int xi = (int)floorf((p.x -  0.0f) * 5.0f);
    int yi = (int)floorf((p.y + 16.0f) * 5.0f);
    int zi = (int)floorf((p.z +  2.0f) * 5.0f);

    if ((unsigned)xi >= VNX || (unsigned)yi >= VNY || (unsigned)zi >= VNZ)
        return;

    int b = bidx[i];
    int flat = ((b * VNZ + zi) * VNY + yi) * VNX + xi;
    atomicMin(&winner[flat], (unsigned int)i);
}

// ---------------------------------------------------------------------------
// Pass 3: gather + transpose to [B, C, Z, Y, X]. Grid-stride (2048 blocks),
// x2 unroll with groups separated by half = n4/2 (R9 structure, neutral but
// kept as base). SINGLE CHANGE vs R9: output stores are PLAIN CACHED stores,
// not non-temporal — fills prove cached store streams hit 6.7 TB/s; NT was
// the untested variable in the slow gather.
// ---------------------------------------------------------------------------
__global__ void vox_gather_kernel(const u32x4* __restrict__ winner4,
                                  const f32x4* __restrict__ feats,
                                  float* __restrict__ out,
                                  unsigned int n, int half) {
    int stride = gridDim.x * blockDim.x;
    const f32x4 zero = { 0.f, 0.f, 0.f, 0.f };

    for (int t = blockIdx.x * blockDim.x + threadIdx.x; t < half; t += stride) {
        u32x4 wa = __builtin_nontemporal_load(&winner4[t]);
        u32x4 wb = __builtin_nontemporal_load(&winner4[t + half]);

        f32x4 a0 = (wa.x < n) ? feats[wa.x] : zero;
        f32x4 a1 = (wa.y < n) ? feats[wa.y] : zero;
        f32x4 a2 = (wa.z < n) ? feats[wa.z] : zero;
        f32x4 a3 = (wa.w < n) ? feats[wa.w] : zero;
        f32x4 b0 = (wb.x < n) ? feats[wb.x] : zero;
        f32x4 b1 = (wb.y < n) ? feats[wb.y] : zero;
        f32x4 b2 = (wb.z < n) ? feats[wb.z] : zero;
        f32x4 b3 = (wb.w < n) ? feats[wb.w] : zero;

        int v = t * 4;                   // 4 consecutive voxels, same batch
        int b = v / PLANE;               // PLANE % 4 == 0
        int r = v - b * PLANE;
        // group t      -> batch b,   group t+half -> batch b+4
        float* baseA = out + (size_t)b * (VC * (size_t)PLANE) + r;
        float* baseB = baseA + 16 * (size_t)PLANE;   // (b+4)*VC*PLANE + r

        f32x4 ca0 = { a0.x, a1.x, a2.x, a3.x };
        f32x4 ca1 = { a0.y, a1.y, a2.y, a3.y };
        f32x4 ca2 = { a0.z, a1.z, a2.z, a3.z };
        f32x4 ca3 = { a0.w, a1.w, a2.w, a3.w };
        f32x4 cb0 = { b0.x, b1.x, b2.x, b3.x };
        f32x4 cb1 = { b0.y, b1.y, b2.y, b3.y };
        f32x4 cb2 = { b0.z, b1.z, b2.z, b3.z };
        f32x4 cb3 = { b0.w, b1.w, b2.w, b3.w };

        *(f32x4*)(baseA + 0 * (size_t)PLANE) = ca0;
        *(f32x4*)(baseA + 1 * (size_t)PLANE) = ca1;
        *(f32x4*)(baseA + 2 * (size_t)PLANE) = ca2;
        *(f32x4*)(baseA + 3 * (size_t)PLANE) = ca3;
        *(f32x4*)(baseB + 0 * (size_t)PLANE) = cb0;
        *(f32x4*)(baseB + 1 * (size_t)PLANE) = cb1;
        *(f32x4*)(baseB + 2 * (size_t)PLANE) = cb2;
        *(f32x4*)(baseB + 3 * (size_t)PLANE) = cb3;
    }
}

// ---------------------------------------------------------------------------
extern "C" void kernel_launch(void* const* d_in, const int* in_sizes, int n_in,
                              void* d_out, int out_size, void* d_ws, size_t ws_size,
                              hipStream_t stream) {
    const float* rdr  = (const float*)d_in[0];   // [N,4] f32
    const int*   bidx = (const int*)d_in[1];     // [N] int32 on device
    int n = in_sizes[1];

    int G    = out_size / VC;                    // 22,118,400 voxels
    int n4   = G / 4;                            // winner uint4 count
    int half = n4 / 2;                           // 4-batch split point

    unsigned int* winner = (unsigned int*)d_ws;  // 88.5 MB (ws is ~1.4 GB)

    int block = 256;
    int grid_dense = 2048;                       // grid-stride, 8 blocks/CU

    // Pass 1: sentinel init (normal stores)
    vox_init_kernel<<<grid_dense, block, 0, stream>>>((u32x4*)winner, n4);

    // Pass 2: scatter min point-id per voxel
    vox_points_kernel<<<(n + block - 1) / block, block, 0, stream>>>(
        (const float4*)rdr, bidx, winner, n);

    // Pass 3: gather + channel transpose, cached stores
    vox_gather_kernel<<<grid_dense, block, 0, stream>>>(
        (const u32x4*)winner, (const f32x4*)rdr, (float*)d_out,
        (unsigned int)n, half);
}

// Round 11
// 160.263 us; speedup vs baseline: 1.1909x; 1.1909x over previous
//
#include <hip/hip_runtime.h>

// Problem constants (match reference module)
#define VNX 360
#define VNY 160
#define VNZ 48
#define VC 4
static constexpr int PLANE = VNZ * VNY * VNX;   // 2,764,800 voxels per batch

typedef unsigned int u32x4 __attribute__((ext_vector_type(4)));
typedef float        f32x4 __attribute__((ext_vector_type(4)));

// ---------------------------------------------------------------------------
// Pass 2: per-point voxelization, first-point-wins via atomicMin(pid).
// Binning: (p - lo) * 5.0f (NOT /0.2f) — matches XLA-CPU fast-math
// reciprocal rewrite; verified bit-exact in round 4.
// ---------------------------------------------------------------------------
__global__ void vox_points_kernel(const float4* __restrict__ pts,
                                  const int* __restrict__ bidx,
                                  unsigned int* __restrict__ winner,
                                  int n) {
    int i = blockIdx.x * blockDim.x + threadIdx.x;
    if (i >= n) return;

    float4 p = pts[i];  // x, y, z, power
    int xi = (int)floorf((p.x -  0.0f) * 5.0f);
    int yi = (int)floorf((p.y + 16.0f) * 5.0f);
    int zi = (int)floorf((p.z +  2.0f) * 5.0f);

    if ((unsigned)xi >= VNX || (unsigned)yi >= VNY || (unsigned)zi >= VNZ)
        return;

    int b = bidx[i];
    int flat = ((b * VNZ + zi) * VNY + yi) * VNX + xi;
    atomicMin(&winner[flat], (unsigned int)i);
}

// ---------------------------------------------------------------------------
// Pass 3: gather + transpose to [B, C, Z, Y, X]. R5's exact form:
// grid-stride 2048 blocks, NT winner loads (read-once), NT output stores
// (R10 proved cached stores regress: L2 dirty-line pressure).
// ---------------------------------------------------------------------------
__global__ void vox_gather_kernel(const u32x4* __restrict__ winner4,
                                  const f32x4* __restrict__ feats,
                                  float* __restrict__ out,
                                  unsigned int n, int nvox4) {
    int stride = gridDim.x * blockDim.x;
    const f32x4 zero = { 0.f, 0.f, 0.f, 0.f };

    for (int t = blockIdx.x * blockDim.x + threadIdx.x; t < nvox4; t += stride) {
        u32x4 w = __builtin_nontemporal_load(&winner4[t]);

        f32x4 f0 = (w.x < n) ? feats[w.x] : zero;
        f32x4 f1 = (w.y < n) ? feats[w.y] : zero;
        f32x4 f2 = (w.z < n) ? feats[w.z] : zero;
        f32x4 f3 = (w.w < n) ? feats[w.w] : zero;

        int v = t * 4;                   // 4 consecutive voxels, same batch
        int b = v / PLANE;               // PLANE % 4 == 0
        int r = v - b * PLANE;
        float* base = out + (size_t)b * (VC * (size_t)PLANE) + r;

        f32x4 c0 = { f0.x, f1.x, f2.x, f3.x };
        f32x4 c1 = { f0.y, f1.y, f2.y, f3.y };
        f32x4 c2 = { f0.z, f1.z, f2.z, f3.z };
        f32x4 c3 = { f0.w, f1.w, f2.w, f3.w };
        __builtin_nontemporal_store(c0, (f32x4*)(base + 0 * (size_t)PLANE));
        __builtin_nontemporal_store(c1, (f32x4*)(base + 1 * (size_t)PLANE));
        __builtin_nontemporal_store(c2, (f32x4*)(base + 2 * (size_t)PLANE));
        __builtin_nontemporal_store(c3, (f32x4*)(base + 3 * (size_t)PLANE));
    }
}

// ---------------------------------------------------------------------------
extern "C" void kernel_launch(void* const* d_in, const int* in_sizes, int n_in,
                              void* d_out, int out_size, void* d_ws, size_t ws_size,
                              hipStream_t stream) {
    const float* rdr  = (const float*)d_in[0];   // [N,4] f32
    const int*   bidx = (const int*)d_in[1];     // [N] int32 on device
    int n = in_sizes[1];

    int G  = out_size / VC;                      // 22,118,400 voxels
    int n4 = G / 4;                              // winner uint4 count

    unsigned int* winner = (unsigned int*)d_ws;  // 88.5 MB (ws is ~1.4 GB)

    int block = 256;
    int grid_dense = 2048;                       // grid-stride, 8 blocks/CU

    // Pass 1: sentinel init via the tuned rocclr fill (6.7-6.9 TB/s measured
    // on this machine) instead of our hand-rolled grid-stride kernel.
    hipMemsetAsync(winner, 0xFF, (size_t)G * sizeof(unsigned int), stream);

    // Pass 2: scatter min point-id per voxel
    vox_points_kernel<<<(n + block - 1) / block, block, 0, stream>>>(
        (const float4*)rdr, bidx, winner, n);

    // Pass 3: gather + channel transpose (R5 form)
    vox_gather_kernel<<<grid_dense, block, 0, stream>>>(
        (const u32x4*)winner, (const f32x4*)rdr, (float*)d_out,
        (unsigned int)n, n4);
}